// Round 19
// baseline (443.839 us; speedup 1.0000x reference)
//
#include <hip/hip_runtime.h>

#define NB 8
#define NN 256
#define HH 256
#define RR 2048   // NB*NN
#define EPSV 1e-5f

typedef __attribute__((ext_vector_type(8))) _Float16 half8v;  // 8 fp16 = 1 MFMA frag
typedef __attribute__((ext_vector_type(4))) float f32x4;

// 16-lane sum reduction on the VALU via DPP (kept: passed R9-R16)
static __device__ __forceinline__ float dpp_red16(float v){
    int t;
    t = __builtin_amdgcn_update_dpp(0, __float_as_int(v), 0xB1, 0xF, 0xF, true);  // quad_perm [1,0,3,2]
    v += __int_as_float(t);
    t = __builtin_amdgcn_update_dpp(0, __float_as_int(v), 0x4E, 0xF, 0xF, true);  // quad_perm [2,3,0,1]
    v += __int_as_float(t);
    t = __builtin_amdgcn_update_dpp(0, __float_as_int(v), 0x141, 0xF, 0xF, true); // row_half_mirror
    v += __int_as_float(t);
    t = __builtin_amdgcn_update_dpp(0, __float_as_int(v), 0x140, 0xF, 0xF, true); // row_mirror
    v += __int_as_float(t);
    return v;
}

struct f3v { float x, y, z; };

// ---------------- fused embedding + BN partial stats ----------------
__global__ __launch_bounds__(256) void k_embstat(const float* __restrict__ nodef,
    const float* __restrict__ embW, const float* __restrict__ embb,
    float* __restrict__ buf1, float* __restrict__ part)
{
    int g = blockIdx.x, c = threadIdx.x;
    float w[6];
    #pragma unroll
    for(int k=0;k<6;k++) w[k] = embW[c*6+k];
    float bb = embb[c];
    float s=0.f, q=0.f;
    for(int rr=0; rr<32; rr++){
        int r = g*32 + rr;
        const float* nr = nodef + r*6;
        float acc = bb;
        #pragma unroll
        for(int k=0;k<6;k++) acc += nr[k]*w[k];
        buf1[r*HH + c] = acc;
        s += acc; q += acc*acc;
    }
    part[g*512 + c]       = s;
    part[g*512 + 256 + c] = q;
}

// ---------------- batchnorm stats (layer loop) ----------------
__global__ __launch_bounds__(256) void k_bnstat_partial(const float* __restrict__ x, float* __restrict__ part)
{
    int g = blockIdx.x, c = threadIdx.x;
    float s=0.f, q=0.f;
    #pragma unroll
    for(int rr=0; rr<32; rr++){
        float v = x[(g*32+rr)*HH + c];
        s += v; q += v*v;
    }
    part[g*512 + c]       = s;
    part[g*512 + 256 + c] = q;
}

__global__ __launch_bounds__(256) void k_bnstat_final(const float* __restrict__ part,
    const float* __restrict__ gam, const float* __restrict__ bet,
    float* __restrict__ scale, float* __restrict__ shift)
{
    int c = threadIdx.x;
    float s=0.f, q=0.f;
    for(int g=0; g<64; g++){ s += part[g*512+c]; q += part[g*512+256+c]; }
    float m  = s * (1.f/RR);
    float v  = q * (1.f/RR) - m*m;
    float sc = gam[c] * rsqrtf(v + EPSV);
    scale[c] = sc;
    shift[c] = bet[c] - m*sc;
}

__global__ __launch_bounds__(256) void k_bnapply_relu(const float* __restrict__ x,
    const float* __restrict__ scale, const float* __restrict__ shift, float* __restrict__ emb)
{
    int e = blockIdx.x*256 + threadIdx.x;
    int c = threadIdx.x;
    float v = x[e]*scale[c] + shift[c];
    emb[e] = v > 0.f ? v : 0.f;
}

__global__ __launch_bounds__(256) void k_bnapply_res(const float* __restrict__ x,
    const float* __restrict__ scale, const float* __restrict__ shift, float* __restrict__ emb)
{
    int e = blockIdx.x*256 + threadIdx.x;
    int c = threadIdx.x;
    emb[e] += x[e]*scale[c] + shift[c];
}

// ---------------- er_sum + deg (tree reduction; trunk order frozen) ----------------
__global__ __launch_bounds__(256) void k_ersum_deg(const int* __restrict__ adj,
    const float* __restrict__ ef, float* __restrict__ ersum, float* __restrict__ degv)
{
    __shared__ float sd[4][256];
    int bid = blockIdx.x;
    int b = bid >> 8, j = bid & 255;
    int i = threadIdx.x;
    float mf = adj[j*NN + i] > 0 ? 1.f : 0.f;
    int base = ((b*NN + i)*NN + j)*15 + 12;
    sd[0][i] = mf * ef[base+0];
    sd[1][i] = mf * ef[base+1];
    sd[2][i] = mf * ef[base+2];
    sd[3][i] = mf;
    __syncthreads();
    for(int s=128; s>0; s>>=1){
        if(i < s){
            sd[0][i]+=sd[0][i+s]; sd[1][i]+=sd[1][i+s];
            sd[2][i]+=sd[2][i+s]; sd[3][i]+=sd[3][i+s];
        }
        __syncthreads();
    }
    if(i==0){
        ersum[(b*NN+j)*3+0] = sd[0][0];
        ersum[(b*NN+j)*3+1] = sd[1][0];
        ersum[(b*NN+j)*3+2] = sd[2][0];
        if(b==0) degv[j] = sd[3][0];
    }
}

// ---------------- generic f32 tiled matmul (proven trunk body) ----------------
__global__ __launch_bounds__(256) void k_mm(const float* __restrict__ A1, const float* __restrict__ A2,
    const float* __restrict__ W, int K, int ldw, int woff,
    const float* __restrict__ bias, int dorelu, float* __restrict__ C, int Co)
{
    __shared__ float As[32][20];
    __shared__ float Ws[64][20];
    int tid = threadIdx.x;
    int c0 = blockIdx.x*64, r0 = blockIdx.y*32;
    int tx = tid & 15, ty = tid >> 4;
    float acc[2][4] = {};
    for(int k0=0; k0<K; k0+=16){
        #pragma unroll
        for(int it=0; it<2; it++){
            int e = tid + it*256;
            int r = e >> 4, kk = e & 15;
            int k = k0 + kk;
            As[r][kk] = (k < 256) ? A1[(r0+r)*HH + k] : A2[(r0+r)*HH + (k-256)];
        }
        #pragma unroll
        for(int it=0; it<4; it++){
            int e = tid + it*256;
            int r = e >> 4, kk = e & 15;
            Ws[r][kk] = W[(c0+r)*ldw + woff + k0 + kk];
        }
        __syncthreads();
        #pragma unroll
        for(int kv=0; kv<4; kv++){
            float a4[2][4], w4[4][4];
            #pragma unroll
            for(int i=0;i<2;i++){
                float4 t1 = *reinterpret_cast<const float4*>(&As[ty*2+i][kv*4]);
                a4[i][0]=t1.x; a4[i][1]=t1.y; a4[i][2]=t1.z; a4[i][3]=t1.w;
            }
            #pragma unroll
            for(int i=0;i<4;i++){
                float4 t2 = *reinterpret_cast<const float4*>(&Ws[tx*4+i][kv*4]);
                w4[i][0]=t2.x; w4[i][1]=t2.y; w4[i][2]=t2.z; w4[i][3]=t2.w;
            }
            #pragma unroll
            for(int e=0;e<4;e++)
                #pragma unroll
                for(int i=0;i<2;i++)
                    #pragma unroll
                    for(int j=0;j<4;j++)
                        acc[i][j] += a4[i][e]*w4[j][e];
        }
        __syncthreads();
    }
    #pragma unroll
    for(int i=0;i<2;i++){
        int rg = r0 + ty*2 + i;
        #pragma unroll
        for(int j=0;j<4;j++){
            int cg = c0 + tx*4 + j;
            float v = acc[i][j];
            if(bias) v += bias[cg];
            if(dorelu) v = v > 0.f ? v : 0.f;
            C[rg*Co + cg] = v;
        }
    }
}

// ---------------- msgs = mask @ t + er_sum.We + deg*msg_b (proven trunk body) ----------------
__global__ __launch_bounds__(256) void k_msg(const int* __restrict__ adj, const float* __restrict__ t,
    const float* __restrict__ ersum, const float* __restrict__ degv,
    const float* __restrict__ msgWl, const float* __restrict__ msgbl, float* __restrict__ msgs)
{
    __shared__ float As[32][20];
    __shared__ float Bs[64][20];
    int tid = threadIdx.x;
    int o0 = blockIdx.x*64, j0 = blockIdx.y*32, b = blockIdx.z;
    const float* tb = t + b*NN*HH;
    int tx = tid & 15, ty = tid >> 4;
    float acc[2][4] = {};
    for(int k0=0; k0<NN; k0+=16){
        #pragma unroll
        for(int it=0; it<2; it++){
            int e = tid + it*256;
            int r = e >> 4, kk = e & 15;
            As[r][kk] = adj[(j0+r)*NN + k0 + kk] > 0 ? 1.f : 0.f;
        }
        #pragma unroll
        for(int it=0; it<4; it++){
            int e = tid + it*256;
            int c = e & 63, k2 = e >> 6;
            Bs[c][k2] = tb[(k0+k2)*HH + o0 + c];
        }
        __syncthreads();
        #pragma unroll
        for(int kv=0; kv<4; kv++){
            float a4[2][4], w4[4][4];
            #pragma unroll
            for(int i=0;i<2;i++){
                float4 t1 = *reinterpret_cast<const float4*>(&As[ty*2+i][kv*4]);
                a4[i][0]=t1.x; a4[i][1]=t1.y; a4[i][2]=t1.z; a4[i][3]=t1.w;
            }
            #pragma unroll
            for(int i=0;i<4;i++){
                float4 t2 = *reinterpret_cast<const float4*>(&Bs[tx*4+i][kv*4]);
                w4[i][0]=t2.x; w4[i][1]=t2.y; w4[i][2]=t2.z; w4[i][3]=t2.w;
            }
            #pragma unroll
            for(int e=0;e<4;e++)
                #pragma unroll
                for(int i=0;i<2;i++)
                    #pragma unroll
                    for(int j=0;j<4;j++)
                        acc[i][j] += a4[i][e]*w4[j][e];
        }
        __syncthreads();
    }
    #pragma unroll
    for(int i=0;i<2;i++){
        int jg = j0 + ty*2 + i;
        const float* es = ersum + (b*NN + jg)*3;
        float dg = degv[jg];
        #pragma unroll
        for(int j=0;j<4;j++){
            int og = o0 + tx*4 + j;
            const float* we = msgWl + og*259 + 256;
            float v = acc[i][j] + es[0]*we[0] + es[1]*we[1] + es[2]*we[2] + dg*msgbl[og];
            msgs[(b*NN+jg)*HH + og] = v;
        }
    }
}

// ---------------- pack: W2 -> fp16, gather W1 edge/temporal cols into planes ----------------
__global__ __launch_bounds__(256) void k_pack(const float* __restrict__ fpW2,
    const float* __restrict__ fpW1, unsigned short* __restrict__ w2hf, float* __restrict__ wext)
{
    int t = blockIdx.x*256 + threadIdx.x;
    if(t < 8192){
        _Float16 h = (_Float16)fpW2[t];     // RNE f32->f16
        w2hf[t] = *reinterpret_cast<unsigned short*>(&h);
    }
    if(t < 896){
        int p = t >> 7, o = t & 127;
        wext[p*128 + o] = fpW1[o*519 + 512 + p];
    }
}

// ---------------- fused fingerprint stage: FP16 MFMA, 256-thread blocks (R16 exact) ----------------
__global__ __launch_bounds__(256) void k_fp2(
    const float* __restrict__ aW,      // [B*N][128], already includes +b1
    const float* __restrict__ cW,      // [B*N][128]
    const float* __restrict__ ef, const float* __restrict__ tfe,
    const float* __restrict__ wext,    // [7][128]
    const float* __restrict__ gl1, const float* __restrict__ lb1,
    const unsigned short* __restrict__ w2hf,  // [64][128] fp16
    const float* __restrict__ fpb2,
    const float* __restrict__ g2, const float* __restrict__ lb2,
    const float* __restrict__ fpW3, const float* __restrict__ fpb3,
    float* __restrict__ out)
{
    __shared__ __align__(16) float wextS[896];
    __shared__ __align__(16) float g1S[128], lb1S[128], aWS[128];
    __shared__ __align__(16) float b2S[64], g2S[64], lb2S[64], w3S[64];

    int tid  = threadIdx.x;
    int idx  = blockIdx.x;
    int jt   = idx & 3, ni = (idx >> 2) & 255, b = idx >> 10;

    // stage block-invariant operands (~6 KB)
    #pragma unroll
    for(int e=tid; e<896; e+=256) wextS[e] = wext[e];
    if(tid < 128){
        g1S[tid] = gl1[tid]; lb1S[tid] = lb1[tid];
        aWS[tid] = aW[(b*NN + ni)*128 + tid];
    } else if(tid < 192){
        int p = tid - 128;
        b2S[p] = fpb2[p]; g2S[p] = g2[p]; lb2S[p] = lb2[p]; w3S[p] = fpW3[p];
    }
    __syncthreads();

    int w    = tid >> 6, lane = tid & 63;
    int x    = lane & 15, g = lane >> 4;
    int j0   = jt*64;
    int pos  = w*16 + x;
    int j    = j0 + pos;
    int eb   = (b*NN + ni)*NN + j;

    f3v e3 = *(const f3v*)(ef + eb*15 + 12);
    float er0 = e3.x, er1 = e3.y, er2 = e3.z;
    float4 tv = *(const float4*)(tfe + eb*4);

    const int obase = g*8;
    const float* crow = cW + (b*NN + j)*128;

    // ---- Phase A: h1 for this lane's (row, 32 k-slots), f32
    float h[32];
    float s = 0.f, sq = 0.f;
    #pragma unroll
    for(int c=0;c<4;c++){
        const int o0 = c*32 + obase;
        const float4 a0 = *(const float4*)(aWS + o0);
        const float4 a1 = *(const float4*)(aWS + o0 + 4);
        const float4 c0v = *(const float4*)(crow + o0);
        const float4 c1v = *(const float4*)(crow + o0 + 4);
        float base[8] = {a0.x+c0v.x, a0.y+c0v.y, a0.z+c0v.z, a0.w+c0v.w,
                         a1.x+c1v.x, a1.y+c1v.y, a1.z+c1v.z, a1.w+c1v.w};
        #pragma unroll
        for(int p=0;p<7;p++){
            const float4 q0 = *(const float4*)(wextS + p*128 + o0);
            const float4 q1 = *(const float4*)(wextS + p*128 + o0 + 4);
            float coef = (p==0)?er0:(p==1)?er1:(p==2)?er2:(p==3)?tv.x:(p==4)?tv.y:(p==5)?tv.z:tv.w;
            base[0] += coef*q0.x; base[1] += coef*q0.y; base[2] += coef*q0.z; base[3] += coef*q0.w;
            base[4] += coef*q1.x; base[5] += coef*q1.y; base[6] += coef*q1.z; base[7] += coef*q1.w;
        }
        #pragma unroll
        for(int u=0;u<8;u++){ float v = base[u]; h[c*8+u] = v; s += v; sq += v*v; }
    }

    // LN1: row's 128 dims live in lanes {x, 16+x, 32+x, 48+x}
    s  += __shfl_xor(s, 16);  s  += __shfl_xor(s, 32);
    sq += __shfl_xor(sq, 16); sq += __shfl_xor(sq, 32);
    float m   = s * (1.f/128.f);
    float var = sq * (1.f/128.f) - m*m;
    float rs  = rsqrtf(var + EPSV);

    // normalize + relu + cast -> fp16 A-frags
    half8v fa[4];
    #pragma unroll
    for(int c=0;c<4;c++){
        const int o0 = c*32 + obase;
        const float4 gg0 = *(const float4*)(g1S + o0);
        const float4 gg1 = *(const float4*)(g1S + o0 + 4);
        const float4 bb0 = *(const float4*)(lb1S + o0);
        const float4 bb1 = *(const float4*)(lb1S + o0 + 4);
        float gg[8] = {gg0.x,gg0.y,gg0.z,gg0.w, gg1.x,gg1.y,gg1.z,gg1.w};
        float bb[8] = {bb0.x,bb0.y,bb0.z,bb0.w, bb1.x,bb1.y,bb1.z,bb1.w};
        #pragma unroll
        for(int u=0;u<8;u++){
            float v = (h[c*8+u]-m)*rs*gg[u] + bb[u];
            v = v > 0.f ? v : 0.f;
            fa[c][u] = (_Float16)v;
        }
    }

    // ---- Phase B: 16 FP16 MFMA; B-frag = W2[n0+x][k-slice] from global (L1-hot)
    f32x4 acc[4];
    #pragma unroll
    for(int n=0;n<4;n++){ acc[n].x=0.f; acc[n].y=0.f; acc[n].z=0.f; acc[n].w=0.f; }
    #pragma unroll
    for(int n=0;n<4;n++){
        #pragma unroll
        for(int c=0;c<4;c++){
            half8v bw = *(const half8v*)(w2hf + ((n*16 + x)*128 + c*32 + obase));
            acc[n] = __builtin_amdgcn_mfma_f32_16x16x32_f16(fa[c], bw, acc[n], 0, 0, 0);
        }
    }

    // ---- Phase C: LN2 over 64 outputs; DPP reductions; tables from LDS
    float b2v[4], g2v[4], lb2v[4], w3v[4];
    #pragma unroll
    for(int n=0;n<4;n++){
        int p = n*16 + x;
        b2v[n] = b2S[p]; g2v[n] = g2S[p]; lb2v[n] = lb2S[p]; w3v[n] = w3S[p];
    }
    float b3 = fpb3[0];

    #pragma unroll
    for(int r=0;r<4;r++){
        float hv[4];
        float s2 = 0.f, q2 = 0.f;
        #pragma unroll
        for(int n=0;n<4;n++){
            float v = acc[n][r] + b2v[n];
            hv[n] = v; s2 += v; q2 += v*v;
        }
        s2 = dpp_red16(s2);
        q2 = dpp_red16(q2);
        float m2  = s2*(1.f/64.f);
        float v2  = q2*(1.f/64.f) - m2*m2;
        float rs2 = rsqrtf(v2 + EPSV);
        float fl = 0.f;
        #pragma unroll
        for(int n=0;n<4;n++){
            float v = (hv[n]-m2)*rs2*g2v[n] + lb2v[n];
            v = v > 0.f ? v : 0.f;
            fl += v * w3v[n];
        }
        fl = dpp_red16(fl);
        if(x == 0){
            float v = fl + b3;
            out[(b*NN + ni)*NN + j0 + w*16 + g*4 + r] = v > 0.f ? v : 0.f;
        }
    }
}

extern "C" void kernel_launch(void* const* d_in, const int* in_sizes, int n_in,
                              void* d_out, int out_size, void* d_ws, size_t ws_size,
                              hipStream_t stream) {
    const float* nodef = (const float*)d_in[0];
    const float* ef    = (const float*)d_in[1];
    const float* tfe   = (const float*)d_in[2];
    const int*   adj   = (const int*)d_in[3];
    const float* embW  = (const float*)d_in[4];
    const float* embb  = (const float*)d_in[5];
    const float* nbn_g = (const float*)d_in[6];
    const float* nbn_b = (const float*)d_in[7];
    const float* msgW  = (const float*)d_in[8];
    const float* msgb  = (const float*)d_in[9];
    const float* updW  = (const float*)d_in[10];
    const float* updb  = (const float*)d_in[11];
    const float* bng   = (const float*)d_in[12];
    const float* bnb   = (const float*)d_in[13];
    const float* fpW1  = (const float*)d_in[14];
    const float* fpb1  = (const float*)d_in[15];
    const float* g1    = (const float*)d_in[16];
    const float* lb1   = (const float*)d_in[17];
    const float* fpW2  = (const float*)d_in[18];
    const float* fpb2  = (const float*)d_in[19];
    const float* g2    = (const float*)d_in[20];
    const float* lb2   = (const float*)d_in[21];
    const float* fpW3  = (const float*)d_in[22];
    const float* fpb3  = (const float*)d_in[23];
    float* outp = (float*)d_out;

    float* ws    = (float*)d_ws;
    float* emb   = ws;                 // 524288
    float* buf1  = ws + 524288;        // 524288
    float* msgs  = ws + 1048576;       // 524288
    float* aW    = ws + 1572864;       // 262144
    float* cW    = ws + 1835008;       // 262144
    float* ersum = ws + 2097152;       // 6144
    float* degv  = ws + 2103296;       // 256
    float* scale = ws + 2103552;       // 256
    float* shift = ws + 2103808;       // 256
    float* part  = ws + 2104064;       // 32768
    unsigned short* w2hf = (unsigned short*)(ws + 2136832); // 8192 ushort
    float* wext  = ws + 2140928;       // 896 (high-water proven)

    // weight packing (independent of everything else)
    k_pack<<<32, 256, 0, stream>>>(fpW2, fpW1, w2hf, wext);

    // fused embedding + BN partial stats, then BN finish + relu
    k_embstat<<<64, 256, 0, stream>>>(nodef, embW, embb, buf1, part);
    k_bnstat_final<<<1, 256, 0, stream>>>(part, nbn_g, nbn_b, scale, shift);
    k_bnapply_relu<<<RR, 256, 0, stream>>>(buf1, scale, shift, emb);

    // loop-invariant edge aggregation + degrees
    k_ersum_deg<<<RR, 256, 0, stream>>>(adj, ef, ersum, degv);

    for(int l=0; l<3; l++){
        const float* msgWl = msgW + l*HH*259;
        const float* msgbl = msgb + l*HH;
        const float* updWl = updW + l*HH*512;
        const float* updbl = updb + l*HH;
        // t = emb @ Wn.T      (256 blocks)
        k_mm<<<dim3(4,64), 256, 0, stream>>>(emb, (const float*)nullptr, msgWl, 256, 259, 0,
                                             (const float*)nullptr, 0, buf1, 256);
        // messages            (256 blocks)
        k_msg<<<dim3(4,8,8), 256, 0, stream>>>(adj, buf1, ersum, degv, msgWl, msgbl, msgs);
        // updated             (256 blocks)
        k_mm<<<dim3(4,64), 256, 0, stream>>>(emb, msgs, updWl, 512, 512, 0,
                                             updbl, 1, buf1, 256);
        // BN + residual
        k_bnstat_partial<<<64, 256, 0, stream>>>(buf1, part);
        k_bnstat_final<<<1, 256, 0, stream>>>(part, bng + l*HH, bnb + l*HH, scale, shift);
        k_bnapply_res<<<RR, 256, 0, stream>>>(buf1, scale, shift, emb);
    }

    // aW = emb @ W1i.T + b1 ; cW = emb @ W1j.T
    k_mm<<<dim3(2,64), 256, 0, stream>>>(emb, (const float*)nullptr, fpW1, 256, 519, 0,
                                         fpb1, 0, aW, 128);
    k_mm<<<dim3(2,64), 256, 0, stream>>>(emb, (const float*)nullptr, fpW1, 256, 519, 256,
                                         (const float*)nullptr, 0, cW, 128);

    // fused fingerprint stage (FP16 MFMA, 256-thread blocks — R16 exact)
    k_fp2<<<NB*NN*4, 256, 0, stream>>>(aW, cW, ef, tfe, wext, g1, lb1,
                                       w2hf, fpb2, g2, lb2, fpW3, fpb3, outp);
}

// Round 20
// 422.364 us; speedup vs baseline: 1.0508x; 1.0508x over previous
//
#include <hip/hip_runtime.h>

#define NB 8
#define NN 256
#define HH 256
#define RR 2048   // NB*NN
#define EPSV 1e-5f

typedef __attribute__((ext_vector_type(8))) _Float16 half8v;  // 8 fp16 = 1 MFMA frag
typedef __attribute__((ext_vector_type(4))) float f32x4;

// 16-lane sum reduction on the VALU via DPP (kept: passed R9-R19)
static __device__ __forceinline__ float dpp_red16(float v){
    int t;
    t = __builtin_amdgcn_update_dpp(0, __float_as_int(v), 0xB1, 0xF, 0xF, true);  // quad_perm [1,0,3,2]
    v += __int_as_float(t);
    t = __builtin_amdgcn_update_dpp(0, __float_as_int(v), 0x4E, 0xF, 0xF, true);  // quad_perm [2,3,0,1]
    v += __int_as_float(t);
    t = __builtin_amdgcn_update_dpp(0, __float_as_int(v), 0x141, 0xF, 0xF, true); // row_half_mirror
    v += __int_as_float(t);
    t = __builtin_amdgcn_update_dpp(0, __float_as_int(v), 0x140, 0xF, 0xF, true); // row_mirror
    v += __int_as_float(t);
    return v;
}

struct f3v { float x, y, z; };

// ---------------- fused embedding + BN partial stats ----------------
__global__ __launch_bounds__(256) void k_embstat(const float* __restrict__ nodef,
    const float* __restrict__ embW, const float* __restrict__ embb,
    float* __restrict__ buf1, float* __restrict__ part)
{
    int g = blockIdx.x, c = threadIdx.x;
    float w[6];
    #pragma unroll
    for(int k=0;k<6;k++) w[k] = embW[c*6+k];
    float bb = embb[c];
    float s=0.f, q=0.f;
    for(int rr=0; rr<32; rr++){
        int r = g*32 + rr;
        const float* nr = nodef + r*6;
        float acc = bb;
        #pragma unroll
        for(int k=0;k<6;k++) acc += nr[k]*w[k];
        buf1[r*HH + c] = acc;
        s += acc; q += acc*acc;
    }
    part[g*512 + c]       = s;
    part[g*512 + 256 + c] = q;
}

// ---------------- batchnorm stats (layer loop) ----------------
__global__ __launch_bounds__(256) void k_bnstat_partial(const float* __restrict__ x, float* __restrict__ part)
{
    int g = blockIdx.x, c = threadIdx.x;
    float s=0.f, q=0.f;
    #pragma unroll
    for(int rr=0; rr<32; rr++){
        float v = x[(g*32+rr)*HH + c];
        s += v; q += v*v;
    }
    part[g*512 + c]       = s;
    part[g*512 + 256 + c] = q;
}

__global__ __launch_bounds__(256) void k_bnstat_final(const float* __restrict__ part,
    const float* __restrict__ gam, const float* __restrict__ bet,
    float* __restrict__ scale, float* __restrict__ shift)
{
    int c = threadIdx.x;
    float s=0.f, q=0.f;
    for(int g=0; g<64; g++){ s += part[g*512+c]; q += part[g*512+256+c]; }
    float m  = s * (1.f/RR);
    float v  = q * (1.f/RR) - m*m;
    float sc = gam[c] * rsqrtf(v + EPSV);
    scale[c] = sc;
    shift[c] = bet[c] - m*sc;
}

__global__ __launch_bounds__(256) void k_bnapply_relu(const float* __restrict__ x,
    const float* __restrict__ scale, const float* __restrict__ shift, float* __restrict__ emb)
{
    int e = blockIdx.x*256 + threadIdx.x;
    int c = threadIdx.x;
    float v = x[e]*scale[c] + shift[c];
    emb[e] = v > 0.f ? v : 0.f;
}

__global__ __launch_bounds__(256) void k_bnapply_res(const float* __restrict__ x,
    const float* __restrict__ scale, const float* __restrict__ shift, float* __restrict__ emb)
{
    int e = blockIdx.x*256 + threadIdx.x;
    int c = threadIdx.x;
    emb[e] += x[e]*scale[c] + shift[c];
}

// ---------------- er_sum + deg (tree reduction; trunk order frozen) ----------------
__global__ __launch_bounds__(256) void k_ersum_deg(const int* __restrict__ adj,
    const float* __restrict__ ef, float* __restrict__ ersum, float* __restrict__ degv)
{
    __shared__ float sd[4][256];
    int bid = blockIdx.x;
    int b = bid >> 8, j = bid & 255;
    int i = threadIdx.x;
    float mf = adj[j*NN + i] > 0 ? 1.f : 0.f;
    int base = ((b*NN + i)*NN + j)*15 + 12;
    sd[0][i] = mf * ef[base+0];
    sd[1][i] = mf * ef[base+1];
    sd[2][i] = mf * ef[base+2];
    sd[3][i] = mf;
    __syncthreads();
    for(int s=128; s>0; s>>=1){
        if(i < s){
            sd[0][i]+=sd[0][i+s]; sd[1][i]+=sd[1][i+s];
            sd[2][i]+=sd[2][i+s]; sd[3][i]+=sd[3][i+s];
        }
        __syncthreads();
    }
    if(i==0){
        ersum[(b*NN+j)*3+0] = sd[0][0];
        ersum[(b*NN+j)*3+1] = sd[1][0];
        ersum[(b*NN+j)*3+2] = sd[2][0];
        if(b==0) degv[j] = sd[3][0];
    }
}

// ---------------- generic f32 tiled matmul (proven trunk body) ----------------
__global__ __launch_bounds__(256) void k_mm(const float* __restrict__ A1, const float* __restrict__ A2,
    const float* __restrict__ W, int K, int ldw, int woff,
    const float* __restrict__ bias, int dorelu, float* __restrict__ C, int Co)
{
    __shared__ float As[32][20];
    __shared__ float Ws[64][20];
    int tid = threadIdx.x;
    int c0 = blockIdx.x*64, r0 = blockIdx.y*32;
    int tx = tid & 15, ty = tid >> 4;
    float acc[2][4] = {};
    for(int k0=0; k0<K; k0+=16){
        #pragma unroll
        for(int it=0; it<2; it++){
            int e = tid + it*256;
            int r = e >> 4, kk = e & 15;
            int k = k0 + kk;
            As[r][kk] = (k < 256) ? A1[(r0+r)*HH + k] : A2[(r0+r)*HH + (k-256)];
        }
        #pragma unroll
        for(int it=0; it<4; it++){
            int e = tid + it*256;
            int r = e >> 4, kk = e & 15;
            Ws[r][kk] = W[(c0+r)*ldw + woff + k0 + kk];
        }
        __syncthreads();
        #pragma unroll
        for(int kv=0; kv<4; kv++){
            float a4[2][4], w4[4][4];
            #pragma unroll
            for(int i=0;i<2;i++){
                float4 t1 = *reinterpret_cast<const float4*>(&As[ty*2+i][kv*4]);
                a4[i][0]=t1.x; a4[i][1]=t1.y; a4[i][2]=t1.z; a4[i][3]=t1.w;
            }
            #pragma unroll
            for(int i=0;i<4;i++){
                float4 t2 = *reinterpret_cast<const float4*>(&Ws[tx*4+i][kv*4]);
                w4[i][0]=t2.x; w4[i][1]=t2.y; w4[i][2]=t2.z; w4[i][3]=t2.w;
            }
            #pragma unroll
            for(int e=0;e<4;e++)
                #pragma unroll
                for(int i=0;i<2;i++)
                    #pragma unroll
                    for(int j=0;j<4;j++)
                        acc[i][j] += a4[i][e]*w4[j][e];
        }
        __syncthreads();
    }
    #pragma unroll
    for(int i=0;i<2;i++){
        int rg = r0 + ty*2 + i;
        #pragma unroll
        for(int j=0;j<4;j++){
            int cg = c0 + tx*4 + j;
            float v = acc[i][j];
            if(bias) v += bias[cg];
            if(dorelu) v = v > 0.f ? v : 0.f;
            C[rg*Co + cg] = v;
        }
    }
}

// ---------------- merged aW/cW matmul: one 256-block launch (bit-identical per-output k-order) ----------------
// blockIdx.x 0..1 -> aW (woff 0, +fpb1); 2..3 -> cW (woff 256, no bias). Body = k_mm verbatim
// with K=256, A2=null, dorelu=0, ldw=519, Co=128 folded in.
__global__ __launch_bounds__(256) void k_mmfp(const float* __restrict__ A1,
    const float* __restrict__ fpW1, const float* __restrict__ fpb1,
    float* __restrict__ aW, float* __restrict__ cW)
{
    __shared__ float As[32][20];
    __shared__ float Ws[64][20];
    int tid = threadIdx.x;
    int bx = blockIdx.x;
    int half = bx >> 1;                       // 0 -> aW, 1 -> cW
    int c0 = (bx & 1)*64, r0 = blockIdx.y*32;
    int woff = half ? 256 : 0;
    const float* bias = half ? (const float*)nullptr : fpb1;
    float* C = half ? cW : aW;
    int tx = tid & 15, ty = tid >> 4;
    float acc[2][4] = {};
    for(int k0=0; k0<256; k0+=16){
        #pragma unroll
        for(int it=0; it<2; it++){
            int e = tid + it*256;
            int r = e >> 4, kk = e & 15;
            As[r][kk] = A1[(r0+r)*HH + k0 + kk];
        }
        #pragma unroll
        for(int it=0; it<4; it++){
            int e = tid + it*256;
            int r = e >> 4, kk = e & 15;
            Ws[r][kk] = fpW1[(c0+r)*519 + woff + k0 + kk];
        }
        __syncthreads();
        #pragma unroll
        for(int kv=0; kv<4; kv++){
            float a4[2][4], w4[4][4];
            #pragma unroll
            for(int i=0;i<2;i++){
                float4 t1 = *reinterpret_cast<const float4*>(&As[ty*2+i][kv*4]);
                a4[i][0]=t1.x; a4[i][1]=t1.y; a4[i][2]=t1.z; a4[i][3]=t1.w;
            }
            #pragma unroll
            for(int i=0;i<4;i++){
                float4 t2 = *reinterpret_cast<const float4*>(&Ws[tx*4+i][kv*4]);
                w4[i][0]=t2.x; w4[i][1]=t2.y; w4[i][2]=t2.z; w4[i][3]=t2.w;
            }
            #pragma unroll
            for(int e=0;e<4;e++)
                #pragma unroll
                for(int i=0;i<2;i++)
                    #pragma unroll
                    for(int j=0;j<4;j++)
                        acc[i][j] += a4[i][e]*w4[j][e];
        }
        __syncthreads();
    }
    #pragma unroll
    for(int i=0;i<2;i++){
        int rg = r0 + ty*2 + i;
        #pragma unroll
        for(int j=0;j<4;j++){
            int cg = c0 + tx*4 + j;
            float v = acc[i][j];
            if(bias) v += bias[cg];
            C[rg*128 + cg] = v;
        }
    }
}

// ---------------- msgs = mask @ t + er_sum.We + deg*msg_b (proven trunk body) ----------------
__global__ __launch_bounds__(256) void k_msg(const int* __restrict__ adj, const float* __restrict__ t,
    const float* __restrict__ ersum, const float* __restrict__ degv,
    const float* __restrict__ msgWl, const float* __restrict__ msgbl, float* __restrict__ msgs)
{
    __shared__ float As[32][20];
    __shared__ float Bs[64][20];
    int tid = threadIdx.x;
    int o0 = blockIdx.x*64, j0 = blockIdx.y*32, b = blockIdx.z;
    const float* tb = t + b*NN*HH;
    int tx = tid & 15, ty = tid >> 4;
    float acc[2][4] = {};
    for(int k0=0; k0<NN; k0+=16){
        #pragma unroll
        for(int it=0; it<2; it++){
            int e = tid + it*256;
            int r = e >> 4, kk = e & 15;
            As[r][kk] = adj[(j0+r)*NN + k0 + kk] > 0 ? 1.f : 0.f;
        }
        #pragma unroll
        for(int it=0; it<4; it++){
            int e = tid + it*256;
            int c = e & 63, k2 = e >> 6;
            Bs[c][k2] = tb[(k0+k2)*HH + o0 + c];
        }
        __syncthreads();
        #pragma unroll
        for(int kv=0; kv<4; kv++){
            float a4[2][4], w4[4][4];
            #pragma unroll
            for(int i=0;i<2;i++){
                float4 t1 = *reinterpret_cast<const float4*>(&As[ty*2+i][kv*4]);
                a4[i][0]=t1.x; a4[i][1]=t1.y; a4[i][2]=t1.z; a4[i][3]=t1.w;
            }
            #pragma unroll
            for(int i=0;i<4;i++){
                float4 t2 = *reinterpret_cast<const float4*>(&Bs[tx*4+i][kv*4]);
                w4[i][0]=t2.x; w4[i][1]=t2.y; w4[i][2]=t2.z; w4[i][3]=t2.w;
            }
            #pragma unroll
            for(int e=0;e<4;e++)
                #pragma unroll
                for(int i=0;i<2;i++)
                    #pragma unroll
                    for(int j=0;j<4;j++)
                        acc[i][j] += a4[i][e]*w4[j][e];
        }
        __syncthreads();
    }
    #pragma unroll
    for(int i=0;i<2;i++){
        int jg = j0 + ty*2 + i;
        const float* es = ersum + (b*NN + jg)*3;
        float dg = degv[jg];
        #pragma unroll
        for(int j=0;j<4;j++){
            int og = o0 + tx*4 + j;
            const float* we = msgWl + og*259 + 256;
            float v = acc[i][j] + es[0]*we[0] + es[1]*we[1] + es[2]*we[2] + dg*msgbl[og];
            msgs[(b*NN+jg)*HH + og] = v;
        }
    }
}

// ---------------- pack: W2 -> fp16, gather W1 edge/temporal cols into planes ----------------
__global__ __launch_bounds__(256) void k_pack(const float* __restrict__ fpW2,
    const float* __restrict__ fpW1, unsigned short* __restrict__ w2hf, float* __restrict__ wext)
{
    int t = blockIdx.x*256 + threadIdx.x;
    if(t < 8192){
        _Float16 h = (_Float16)fpW2[t];     // RNE f32->f16
        w2hf[t] = *reinterpret_cast<unsigned short*>(&h);
    }
    if(t < 896){
        int p = t >> 7, o = t & 127;
        wext[p*128 + o] = fpW1[o*519 + 512 + p];
    }
}

// ---------------- fused fingerprint stage: FP16 MFMA, 256-thread blocks (R16/R19 exact) ----------------
__global__ __launch_bounds__(256) void k_fp2(
    const float* __restrict__ aW,      // [B*N][128], already includes +b1
    const float* __restrict__ cW,      // [B*N][128]
    const float* __restrict__ ef, const float* __restrict__ tfe,
    const float* __restrict__ wext,    // [7][128]
    const float* __restrict__ gl1, const float* __restrict__ lb1,
    const unsigned short* __restrict__ w2hf,  // [64][128] fp16
    const float* __restrict__ fpb2,
    const float* __restrict__ g2, const float* __restrict__ lb2,
    const float* __restrict__ fpW3, const float* __restrict__ fpb3,
    float* __restrict__ out)
{
    __shared__ __align__(16) float wextS[896];
    __shared__ __align__(16) float g1S[128], lb1S[128], aWS[128];
    __shared__ __align__(16) float b2S[64], g2S[64], lb2S[64], w3S[64];

    int tid  = threadIdx.x;
    int idx  = blockIdx.x;
    int jt   = idx & 3, ni = (idx >> 2) & 255, b = idx >> 10;

    // stage block-invariant operands (~6 KB)
    #pragma unroll
    for(int e=tid; e<896; e+=256) wextS[e] = wext[e];
    if(tid < 128){
        g1S[tid] = gl1[tid]; lb1S[tid] = lb1[tid];
        aWS[tid] = aW[(b*NN + ni)*128 + tid];
    } else if(tid < 192){
        int p = tid - 128;
        b2S[p] = fpb2[p]; g2S[p] = g2[p]; lb2S[p] = lb2[p]; w3S[p] = fpW3[p];
    }
    __syncthreads();

    int w    = tid >> 6, lane = tid & 63;
    int x    = lane & 15, g = lane >> 4;
    int j0   = jt*64;
    int pos  = w*16 + x;
    int j    = j0 + pos;
    int eb   = (b*NN + ni)*NN + j;

    f3v e3 = *(const f3v*)(ef + eb*15 + 12);
    float er0 = e3.x, er1 = e3.y, er2 = e3.z;
    float4 tv = *(const float4*)(tfe + eb*4);

    const int obase = g*8;
    const float* crow = cW + (b*NN + j)*128;

    // ---- Phase A: h1 for this lane's (row, 32 k-slots), f32
    float h[32];
    float s = 0.f, sq = 0.f;
    #pragma unroll
    for(int c=0;c<4;c++){
        const int o0 = c*32 + obase;
        const float4 a0 = *(const float4*)(aWS + o0);
        const float4 a1 = *(const float4*)(aWS + o0 + 4);
        const float4 c0v = *(const float4*)(crow + o0);
        const float4 c1v = *(const float4*)(crow + o0 + 4);
        float base[8] = {a0.x+c0v.x, a0.y+c0v.y, a0.z+c0v.z, a0.w+c0v.w,
                         a1.x+c1v.x, a1.y+c1v.y, a1.z+c1v.z, a1.w+c1v.w};
        #pragma unroll
        for(int p=0;p<7;p++){
            const float4 q0 = *(const float4*)(wextS + p*128 + o0);
            const float4 q1 = *(const float4*)(wextS + p*128 + o0 + 4);
            float coef = (p==0)?er0:(p==1)?er1:(p==2)?er2:(p==3)?tv.x:(p==4)?tv.y:(p==5)?tv.z:tv.w;
            base[0] += coef*q0.x; base[1] += coef*q0.y; base[2] += coef*q0.z; base[3] += coef*q0.w;
            base[4] += coef*q1.x; base[5] += coef*q1.y; base[6] += coef*q1.z; base[7] += coef*q1.w;
        }
        #pragma unroll
        for(int u=0;u<8;u++){ float v = base[u]; h[c*8+u] = v; s += v; sq += v*v; }
    }

    // LN1: row's 128 dims live in lanes {x, 16+x, 32+x, 48+x}
    s  += __shfl_xor(s, 16);  s  += __shfl_xor(s, 32);
    sq += __shfl_xor(sq, 16); sq += __shfl_xor(sq, 32);
    float m   = s * (1.f/128.f);
    float var = sq * (1.f/128.f) - m*m;
    float rs  = rsqrtf(var + EPSV);

    // normalize + relu + cast -> fp16 A-frags
    half8v fa[4];
    #pragma unroll
    for(int c=0;c<4;c++){
        const int o0 = c*32 + obase;
        const float4 gg0 = *(const float4*)(g1S + o0);
        const float4 gg1 = *(const float4*)(g1S + o0 + 4);
        const float4 bb0 = *(const float4*)(lb1S + o0);
        const float4 bb1 = *(const float4*)(lb1S + o0 + 4);
        float gg[8] = {gg0.x,gg0.y,gg0.z,gg0.w, gg1.x,gg1.y,gg1.z,gg1.w};
        float bb[8] = {bb0.x,bb0.y,bb0.z,bb0.w, bb1.x,bb1.y,bb1.z,bb1.w};
        #pragma unroll
        for(int u=0;u<8;u++){
            float v = (h[c*8+u]-m)*rs*gg[u] + bb[u];
            v = v > 0.f ? v : 0.f;
            fa[c][u] = (_Float16)v;
        }
    }

    // ---- Phase B: 16 FP16 MFMA; B-frag = W2[n0+x][k-slice] from global (L1-hot)
    f32x4 acc[4];
    #pragma unroll
    for(int n=0;n<4;n++){ acc[n].x=0.f; acc[n].y=0.f; acc[n].z=0.f; acc[n].w=0.f; }
    #pragma unroll
    for(int n=0;n<4;n++){
        #pragma unroll
        for(int c=0;c<4;c++){
            half8v bw = *(const half8v*)(w2hf + ((n*16 + x)*128 + c*32 + obase));
            acc[n] = __builtin_amdgcn_mfma_f32_16x16x32_f16(fa[c], bw, acc[n], 0, 0, 0);
        }
    }

    // ---- Phase C: LN2 over 64 outputs; DPP reductions; tables from LDS
    float b2v[4], g2v[4], lb2v[4], w3v[4];
    #pragma unroll
    for(int n=0;n<4;n++){
        int p = n*16 + x;
        b2v[n] = b2S[p]; g2v[n] = g2S[p]; lb2v[n] = lb2S[p]; w3v[n] = w3S[p];
    }
    float b3 = fpb3[0];

    #pragma unroll
    for(int r=0;r<4;r++){
        float hv[4];
        float s2 = 0.f, q2 = 0.f;
        #pragma unroll
        for(int n=0;n<4;n++){
            float v = acc[n][r] + b2v[n];
            hv[n] = v; s2 += v; q2 += v*v;
        }
        s2 = dpp_red16(s2);
        q2 = dpp_red16(q2);
        float m2  = s2*(1.f/64.f);
        float v2  = q2*(1.f/64.f) - m2*m2;
        float rs2 = rsqrtf(v2 + EPSV);
        float fl = 0.f;
        #pragma unroll
        for(int n=0;n<4;n++){
            float v = (hv[n]-m2)*rs2*g2v[n] + lb2v[n];
            v = v > 0.f ? v : 0.f;
            fl += v * w3v[n];
        }
        fl = dpp_red16(fl);
        if(x == 0){
            float v = fl + b3;
            out[(b*NN + ni)*NN + j0 + w*16 + g*4 + r] = v > 0.f ? v : 0.f;
        }
    }
}

extern "C" void kernel_launch(void* const* d_in, const int* in_sizes, int n_in,
                              void* d_out, int out_size, void* d_ws, size_t ws_size,
                              hipStream_t stream) {
    const float* nodef = (const float*)d_in[0];
    const float* ef    = (const float*)d_in[1];
    const float* tfe   = (const float*)d_in[2];
    const int*   adj   = (const int*)d_in[3];
    const float* embW  = (const float*)d_in[4];
    const float* embb  = (const float*)d_in[5];
    const float* nbn_g = (const float*)d_in[6];
    const float* nbn_b = (const float*)d_in[7];
    const float* msgW  = (const float*)d_in[8];
    const float* msgb  = (const float*)d_in[9];
    const float* updW  = (const float*)d_in[10];
    const float* updb  = (const float*)d_in[11];
    const float* bng   = (const float*)d_in[12];
    const float* bnb   = (const float*)d_in[13];
    const float* fpW1  = (const float*)d_in[14];
    const float* fpb1  = (const float*)d_in[15];
    const float* g1    = (const float*)d_in[16];
    const float* lb1   = (const float*)d_in[17];
    const float* fpW2  = (const float*)d_in[18];
    const float* fpb2  = (const float*)d_in[19];
    const float* g2    = (const float*)d_in[20];
    const float* lb2   = (const float*)d_in[21];
    const float* fpW3  = (const float*)d_in[22];
    const float* fpb3  = (const float*)d_in[23];
    float* outp = (float*)d_out;

    float* ws    = (float*)d_ws;
    float* emb   = ws;                 // 524288
    float* buf1  = ws + 524288;        // 524288
    float* msgs  = ws + 1048576;       // 524288
    float* aW    = ws + 1572864;       // 262144
    float* cW    = ws + 1835008;       // 262144
    float* ersum = ws + 2097152;       // 6144
    float* degv  = ws + 2103296;       // 256
    float* scale = ws + 2103552;       // 256
    float* shift = ws + 2103808;       // 256
    float* part  = ws + 2104064;       // 32768
    unsigned short* w2hf = (unsigned short*)(ws + 2136832); // 8192 ushort
    float* wext  = ws + 2140928;       // 896 (high-water proven)

    // weight packing (independent of everything else)
    k_pack<<<32, 256, 0, stream>>>(fpW2, fpW1, w2hf, wext);

    // fused embedding + BN partial stats, then BN finish + relu
    k_embstat<<<64, 256, 0, stream>>>(nodef, embW, embb, buf1, part);
    k_bnstat_final<<<1, 256, 0, stream>>>(part, nbn_g, nbn_b, scale, shift);
    k_bnapply_relu<<<RR, 256, 0, stream>>>(buf1, scale, shift, emb);

    // loop-invariant edge aggregation + degrees
    k_ersum_deg<<<RR, 256, 0, stream>>>(adj, ef, ersum, degv);

    for(int l=0; l<3; l++){
        const float* msgWl = msgW + l*HH*259;
        const float* msgbl = msgb + l*HH;
        const float* updWl = updW + l*HH*512;
        const float* updbl = updb + l*HH;
        // t = emb @ Wn.T      (256 blocks)
        k_mm<<<dim3(4,64), 256, 0, stream>>>(emb, (const float*)nullptr, msgWl, 256, 259, 0,
                                             (const float*)nullptr, 0, buf1, 256);
        // messages            (256 blocks)
        k_msg<<<dim3(4,8,8), 256, 0, stream>>>(adj, buf1, ersum, degv, msgWl, msgbl, msgs);
        // updated             (256 blocks)
        k_mm<<<dim3(4,64), 256, 0, stream>>>(emb, msgs, updWl, 512, 512, 0,
                                             updbl, 1, buf1, 256);
        // BN + residual
        k_bnstat_partial<<<64, 256, 0, stream>>>(buf1, part);
        k_bnstat_final<<<1, 256, 0, stream>>>(part, bng + l*HH, bnb + l*HH, scale, shift);
        k_bnapply_res<<<RR, 256, 0, stream>>>(buf1, scale, shift, emb);
    }

    // aW = emb @ W1i.T + b1 ; cW = emb @ W1j.T  — one full-fill 256-block launch
    k_mmfp<<<dim3(4,64), 256, 0, stream>>>(emb, fpW1, fpb1, aW, cW);

    // fused fingerprint stage (FP16 MFMA, 256-thread blocks)
    k_fp2<<<NB*NN*4, 256, 0, stream>>>(aW, cW, ef, tfe, wext, g1, lb1,
                                       w2hf, fpb2, g2, lb2, fpW3, fpb3, outp);
}